// Round 3
// baseline (348.880 us; speedup 1.0000x reference)
//
#include <hip/hip_runtime.h>

typedef __attribute__((ext_vector_type(8))) _Float16 half8;
typedef __attribute__((ext_vector_type(4))) _Float16 half4;
typedef __attribute__((ext_vector_type(4))) float f32x4;
typedef __attribute__((ext_vector_type(16))) float f32x16;

#define CDIM 256
#define NDIM 4096
#define MFMAH(a, b, c) __builtin_amdgcn_mfma_f32_16x16x32_f16((a), (b), (c), 0, 0, 0)
#define MFMA32(a, b, c) __builtin_amdgcn_mfma_f32_32x32x16_f16((a), (b), (c), 0, 0, 0)

// ---------------------------------------------------------------------------
// Cast W matrices to fp16 once per launch (L2-resident afterwards).
// ---------------------------------------------------------------------------
__global__ void cast_w_kernel(const float* __restrict__ Wq,
                              const float* __restrict__ Wk,
                              const float* __restrict__ Wv,
                              _Float16* __restrict__ Wc) {
  int t = blockIdx.x * 256 + threadIdx.x;      // 49152 float4 groups total
  int mat = t >> 14;                            // /16384
  int idx = (t & 16383) * 4;
  const float* W = (mat == 0) ? Wq : (mat == 1 ? Wk : Wv);
  float4 w = *(const float4*)(W + idx);
  half4 h = {(_Float16)w.x, (_Float16)w.y, (_Float16)w.z, (_Float16)w.w};
  *(half4*)(Wc + mat * 65536 + idx) = h;
}

// ---------------------------------------------------------------------------
// Projection (unchanged, round-5 proven): Y[b,o,n] = sum_c W[o,c] X[b,c,n]+b[o]
// Q,K -> [b][n][c]; V -> [b][c][n].
// ---------------------------------------------------------------------------
__global__ __launch_bounds__(256, 2) void proj_kernel(
    const float* __restrict__ queries, const float* __restrict__ keys,
    const _Float16* __restrict__ Wc,
    const float* __restrict__ bq, const float* __restrict__ bk,
    const float* __restrict__ bv,
    _Float16* __restrict__ Qh, _Float16* __restrict__ Kh,
    _Float16* __restrict__ Vh)
{
  const int z = blockIdx.z, p = z >> 3, b = z & 7;
  const float* __restrict__ X = (p == 0) ? queries : keys;
  const _Float16* __restrict__ W = Wc + p * 65536;
  const float* __restrict__ bias = (p == 0) ? bq : (p == 1 ? bk : bv);
  const int n0 = blockIdx.x * 128;

  __shared__ __align__(16) _Float16 Xs[128][264];  // [n][c], 528 B rows

  const int tid = threadIdx.x;
  const int wv = tid >> 6, lane = tid & 63, l16 = lane & 15, quad = lane >> 4;

#pragma unroll
  for (int it = 0; it < 32; ++it) {
    int id = tid + it * 256;
    int c = id >> 5, n4 = id & 31;
    float4 x = *(const float4*)&X[((size_t)(b * CDIM + c)) * NDIM + n0 + n4 * 4];
    Xs[n4 * 4 + 0][c] = (_Float16)x.x;
    Xs[n4 * 4 + 1][c] = (_Float16)x.y;
    Xs[n4 * 4 + 2][c] = (_Float16)x.z;
    Xs[n4 * 4 + 3][c] = (_Float16)x.w;
  }
  __syncthreads();

  f32x4 acc[4][8];
#pragma unroll
  for (int og = 0; og < 4; ++og)
#pragma unroll
    for (int ng = 0; ng < 8; ++ng) acc[og][ng] = (f32x4){0.f, 0.f, 0.f, 0.f};

#pragma unroll
  for (int kc = 0; kc < 8; ++kc) {
    half8 wf[4], xf[8];
#pragma unroll
    for (int og = 0; og < 4; ++og)
      wf[og] = *(const half8*)(W + (wv * 64 + og * 16 + l16) * CDIM + kc * 32 + quad * 8);
#pragma unroll
    for (int ng = 0; ng < 8; ++ng)
      xf[ng] = *(const half8*)&Xs[ng * 16 + l16][kc * 32 + quad * 8];
#pragma unroll
    for (int og = 0; og < 4; ++og)
#pragma unroll
      for (int ng = 0; ng < 8; ++ng)
        acc[og][ng] = MFMAH(wf[og], xf[ng], acc[og][ng]);
  }

#pragma unroll
  for (int og = 0; og < 4; ++og) {
    float4 b4 = *(const float4*)&bias[wv * 64 + og * 16 + quad * 4];
#pragma unroll
    for (int ng = 0; ng < 8; ++ng) {
      const int n = n0 + ng * 16 + l16;
      if (p == 2) {
#pragma unroll
        for (int r = 0; r < 4; ++r) {
          int o = wv * 64 + og * 16 + quad * 4 + r;
          float y = acc[og][ng][r] + ((const float*)&b4)[r];
          Vh[((size_t)(b * CDIM + o)) * NDIM + n] = (_Float16)y;
        }
      } else {
        half4 h4;
#pragma unroll
        for (int r = 0; r < 4; ++r)
          h4[r] = (_Float16)(acc[og][ng][r] + ((const float*)&b4)[r]);
        size_t idx = ((size_t)(b * NDIM + n)) * CDIM + wv * 64 + og * 16 + quad * 4;
        if (p == 0) *(half4*)&Qh[idx] = h4;
        else        *(half4*)&Kh[idx] = h4;
      }
    }
  }
}

// ---------------------------------------------------------------------------
// Flash attention, 32x32x16 MFMA restructure (halves per-FLOP LDS traffic).
//
// QK^T: wave (wi,wj) computes S^T tile D[m=j (wj half)][n=i (wi half)] from
//       K A-frags (LDS, 16 reads/wave vs 32) x Q B-frags (regs, 64 VGPR).
// Softmax: per-wave LOCAL max over its 32 j (15 fmax + xor32); P written to
//       LDS normalized by the local max; (max, partial sum) posted in Mx/Ls.
//       After B2 every wave merges both halves' stats -> running m/l, and the
//       P B-frags are scaled by exp2(lm_half - m_new) in fp16 (pk_mul).
// PV:   computed as O^T = V * P^T -> D[m=c][n=i]; output col = i = lane&31,
//       so the alpha rescale is LANE-UNIFORM: Al/Li/av LDS machinery deleted.
//       V A-frags direct from global (L2-resident), same addresses as before.
// exp -> exp2 domain (mask premultiplied by log2e).
// ---------------------------------------------------------------------------
__global__ __launch_bounds__(256, 2) void attn_kernel(
    const float* __restrict__ queries, const float* __restrict__ mask,
    const _Float16* __restrict__ Qh, const _Float16* __restrict__ Kh,
    const _Float16* __restrict__ Vh, float* __restrict__ out)
{
  const int blk = blockIdx.x, b = blk & 7, it = blk >> 3;  // b=blk&7: XCD L2
  const int i0 = it * 64;

  __shared__ __align__(16) _Float16 Ks[64][264];    // [j][c]  33792 B
  __shared__ __align__(16) _Float16 Ps[2][64][72];  // [i][j]  18432 B (dbuf)
  __shared__ __align__(16) float Mx[2][2][64];      // [pb][wj-half][i] local max
  __shared__ __align__(16) float Ls[2][2][64];      // [pb][wj-half][i] local sum

  const int tid = threadIdx.x;
  const int wv = tid >> 6, lane = tid & 63;
  const int l32 = lane & 31, hk = lane >> 5;        // hk: k-half of fragment
  const int wi = wv >> 1, wj = wv & 1;              // QK tile coords

  const float LOG2E = 1.44269504088896f;

  // Q fragments: B operand (n = i = l32 + wi*32, k = c = kc*16 + hk*8 + t)
  half8 qf[16];
  {
    const size_t qrow = ((size_t)(b * NDIM + i0 + wi * 32 + l32)) * CDIM;
#pragma unroll
    for (int kc = 0; kc < 16; ++kc)
      qf[kc] = *(const half8*)(Qh + qrow + kc * 16 + hk * 8);
  }

  // QK-phase lane row: i = i0 + wi*32 + l32 (mask premul by log2e)
  const float mvalL = mask[(size_t)b * NDIM + i0 + wi * 32 + l32] * LOG2E;
  // per-lane softmax state for i = i0 + t*32 + l32 (t=0,1), kept redundantly
  // and identically by all 4 waves (they read the same Mx/Ls).
  float m_run[2] = {-1e30f, -1e30f};
  float l_run[2] = {0.f, 0.f};

  f32x16 O[2][2];  // [t: i-sub][ct: c-sub]; lane col i = i0 + t*32 + l32
#pragma unroll
  for (int t = 0; t < 2; ++t)
#pragma unroll
    for (int ct = 0; ct < 2; ++ct)
#pragma unroll
      for (int r = 0; r < 16; ++r) O[t][ct][r] = 0.f;

  const _Float16* __restrict__ Kb = Kh + (size_t)b * NDIM * CDIM;
  const _Float16* __restrict__ Vw = Vh + ((size_t)(b * CDIM + wv * 64)) * NDIM;

  for (int jt = 0; jt < 64; ++jt) {
    const int j0 = jt * 64;
    const int pb = jt & 1;
    // stage K tile (Ks reads of jt-1 all complete before B2(jt-1))
#pragma unroll
    for (int st = 0; st < 8; ++st) {
      int id = tid + st * 256;
      int j = id >> 5, c8 = id & 31;
      *(uint4*)&Ks[j][c8 * 8] = *(const uint4*)(Kb + (size_t)(j0 + j) * CDIM + c8 * 8);
    }
    // V A-fragments direct from global (m = c = ct*32+l32, k = j); issued
    // here so the L2 latency hides under QK compute.
    half8 va[2][4];
#pragma unroll
    for (int ct = 0; ct < 2; ++ct)
#pragma unroll
      for (int js = 0; js < 4; ++js)
        va[ct][js] = *(const half8*)(Vw + (size_t)(ct * 32 + l32) * NDIM + j0 + js * 16 + hk * 8);
    __syncthreads();  // B1: Ks staged

    // S^T tile: 16 chained MFMAs split into 2 accumulators (dep-chain relief)
    f32x16 s0, s1;
#pragma unroll
    for (int r = 0; r < 16; ++r) { s0[r] = 0.f; s1[r] = 0.f; }
#pragma unroll
    for (int kc = 0; kc < 16; kc += 2) {
      half8 kfa = *(const half8*)&Ks[wj * 32 + l32][kc * 16 + hk * 8];
      half8 kfb = *(const half8*)&Ks[wj * 32 + l32][(kc + 1) * 16 + hk * 8];
      s0 = MFMA32(kfa, qf[kc], s0);
      s1 = MFMA32(kfb, qf[kc + 1], s1);
    }

    // local softmax over this wave's 32 j (16 in-lane + xor32)
    float a[16];
    float lm = -1e30f;
#pragma unroll
    for (int r = 0; r < 16; ++r) {
      a[r] = (s0[r] + s1[r]) * mvalL;
      lm = fmaxf(lm, a[r]);
    }
    lm = fmaxf(lm, __shfl_xor(lm, 32));
    float psum = 0.f;
#pragma unroll
    for (int rq = 0; rq < 4; ++rq) {
      float p0 = exp2f(a[rq * 4 + 0] - lm);
      float p1 = exp2f(a[rq * 4 + 1] - lm);
      float p2 = exp2f(a[rq * 4 + 2] - lm);
      float p3 = exp2f(a[rq * 4 + 3] - lm);
      psum += (p0 + p1) + (p2 + p3);
      half4 hp = {(_Float16)p0, (_Float16)p1, (_Float16)p2, (_Float16)p3};
      // P[i][j]: i = wi*32+l32, j = wj*32 + rq*8 + hk*4 + (0..3)
      *(half4*)&Ps[pb][wi * 32 + l32][wj * 32 + rq * 8 + hk * 4] = hp;
    }
    psum += __shfl_xor(psum, 32);
    if (hk == 0) {
      Mx[pb][wj][wi * 32 + l32] = lm;
      Ls[pb][wj][wi * 32 + l32] = psum;
    }
    __syncthreads();  // B2: Ps/Mx/Ls visible

    // merge halves, rescale O (lane-uniform!), O^T += V P^T
#pragma unroll
    for (int t = 0; t < 2; ++t) {
      const int irow = t * 32 + l32;
      const float mx0 = Mx[pb][0][irow];
      const float mx1 = Mx[pb][1][irow];
      const float mnew = fmaxf(m_run[t], fmaxf(mx0, mx1));
      const float alpha = exp2f(m_run[t] - mnew);
      const float f0 = exp2f(mx0 - mnew);
      const float f1 = exp2f(mx1 - mnew);
      l_run[t] = l_run[t] * alpha + Ls[pb][0][irow] * f0 + Ls[pb][1][irow] * f1;
      m_run[t] = mnew;
#pragma unroll
      for (int ct = 0; ct < 2; ++ct)
#pragma unroll
        for (int r = 0; r < 16; ++r) O[t][ct][r] *= alpha;
      const _Float16 hf0 = (_Float16)f0, hf1 = (_Float16)f1;
#pragma unroll
      for (int js = 0; js < 4; ++js) {
        // P^T B-frag: n = i = irow, k = j = js*16 + hk*8 + t8
        half8 pf = *(const half8*)&Ps[pb][irow][js * 16 + hk * 8];
        const _Float16 sc = (js < 2) ? hf0 : hf1;  // j<32 -> half 0
#pragma unroll
        for (int e = 0; e < 8; ++e) pf[e] *= sc;   // packs to v_pk_mul_f16
#pragma unroll
        for (int ct = 0; ct < 2; ++ct)
          O[t][ct] = MFMA32(va[ct][js], pf, O[t][ct]);
      }
    }
  }

  // blended epilogue: O^T layout -> col i = i0+t*32+l32 (lane-uniform 1/l),
  // rows c = wv*64 + ct*32 + (r&3)+8*(r>>2)+4*hk
#pragma unroll
  for (int t = 0; t < 2; ++t) {
    const int i = i0 + t * 32 + l32;
    const float mv = mask[(size_t)b * NDIM + i];
    const float rl = (1.f - mv) / l_run[t];
#pragma unroll
    for (int ct = 0; ct < 2; ++ct) {
#pragma unroll
      for (int r = 0; r < 16; ++r) {
        const int c = wv * 64 + ct * 32 + (r & 3) + 8 * (r >> 2) + 4 * hk;
        const size_t base = ((size_t)(b * CDIM + c)) * NDIM + i;
        out[base] = queries[base] * mv + rl * O[t][ct][r];
      }
    }
  }
}

extern "C" void kernel_launch(void* const* d_in, const int* in_sizes, int n_in,
                              void* d_out, int out_size, void* d_ws, size_t ws_size,
                              hipStream_t stream) {
  const float* queries = (const float*)d_in[0];
  const float* keys    = (const float*)d_in[1];
  const float* mask    = (const float*)d_in[2];
  const float* Wq = (const float*)d_in[3];
  const float* bq = (const float*)d_in[4];
  const float* Wk = (const float*)d_in[5];
  const float* bk = (const float*)d_in[6];
  const float* Wv = (const float*)d_in[7];
  const float* bv = (const float*)d_in[8];
  float* out = (float*)d_out;

  const size_t elems = (size_t)8 * NDIM * CDIM;
  _Float16* Qh = (_Float16*)d_ws;
  _Float16* Kh = Qh + elems;
  _Float16* Vh = Kh + elems;
  _Float16* Wc = Vh + elems;   // 3*65536 fp16

  cast_w_kernel<<<dim3(192), 256, 0, stream>>>(Wq, Wk, Wv, Wc);
  proj_kernel<<<dim3(32, 1, 24), 256, 0, stream>>>(
      queries, keys, Wc, bq, bk, bv, Qh, Kh, Vh);
  attn_kernel<<<dim3(512), 256, 0, stream>>>(
      queries, mask, Qh, Kh, Vh, out);
}